// Round 12
// baseline (56.328 us; speedup 1.0000x reference)
//
#include <hip/hip_runtime.h>

// STN forward, LDS-tiled, one-channel buffer, two passes, 512-thread blocks.
// R12 = R11 + w-geometry fix: lo_w = t0w-4 (4-ALIGNED -> granules are aligned
// float4 and the right-edge clamp min(lo_w+rw, W-4) only affects granules
// PAST the used extent; R11's lo_w=t0w-3 shifted data inside the used range).
// hi_* = min(lo_* + extent - 1, dim - 1). d/h halo = 3, w halo = -4/+3.
// Region 23x23x24 floats = 50,784 B LDS. 8 voxels/thread.

constexpr int B = 2, C = 2, D = 128, H = 128, W = 128;
constexpr int HW  = H * W;
constexpr int DHW = D * HW;
constexpr int TD = 16, TH = 16, TW = 16;
constexpr int RD = 23, RH = 23, RWP = 24;    // region extents (w: 6 granules)
constexpr int CHF = RD * RH * RWP;           // 12696 floats
constexpr int CHG = CHF / 4;                 // 3174 16B granules
constexpr int NT = 512;
constexpr int NFULL = 6;                     // 6*512 = 3072 granules
constexpr int TAILN = CHG - NFULL * NT;      // 102 tail granules

__device__ __forceinline__ void gload_lds16(const float* g, float* l) {
    __builtin_amdgcn_global_load_lds(
        (const __attribute__((address_space(1))) void*)g,
        (__attribute__((address_space(3))) void*)l, 16, 0, 0);
}

__global__ __launch_bounds__(NT) void stn_kernel(
    const float* __restrict__ image,
    const float* __restrict__ ddf,
    float* __restrict__ out)
{
    __shared__ float smem[CHF];              // 50,784 B

    const int blk = blockIdx.x;
    const int b   = blk >> 9;
    const int tb  = blk & 511;
    const int t0d = (tb >> 6) * TD, t0h = ((tb >> 3) & 7) * TH, t0w = (tb & 7) * TW;
    const int lo_d = max(t0d - 3, 0);
    const int lo_h = max(t0h - 3, 0);
    const int lo_w = max(t0w - 4, 0);        // 4-ALIGNED (t0w % 16 == 0)
    const int hi_d = min(lo_d + RD - 1, D - 1);
    const int hi_h = min(lo_h + RH - 1, H - 1);
    const int hi_w = min(lo_w + RWP - 1, W - 1);
    const float* imgb = image + (size_t)b * C * DHW;
    const int tid = threadIdx.x;

    // ---- ddf loads FIRST: 8 voxels/thread = rows (d,hh) and (d,hh+8) ----
    const int dl = tid >> 5, hl = (tid >> 2) & 7, wq = tid & 3;
    const int d = t0d + dl, hh = t0h + hl, w4 = t0w + wq * 4;
    const int sidx0 = d * HW + hh * W + w4;
    const int sidx1 = sidx0 + 8 * W;
    const float* dp = ddf + (size_t)b * 3 * DHW;
    float4 f0d = *reinterpret_cast<const float4*>(dp + sidx0);
    float4 f1d = *reinterpret_cast<const float4*>(dp + sidx1);
    float4 f0h = *reinterpret_cast<const float4*>(dp + DHW + sidx0);
    float4 f1h = *reinterpret_cast<const float4*>(dp + DHW + sidx1);
    float4 f0w = *reinterpret_cast<const float4*>(dp + 2 * DHW + sidx0);
    float4 f1w = *reinterpret_cast<const float4*>(dp + 2 * DHW + sidx1);
    asm volatile("" ::: "memory");

    // granule g -> global offset (row/col clamped at volume edge; clamped
    // w-granules lie beyond the used index range by construction)
    auto gsrc_off = [&](int g) {
        int row = g / 6;
        int rw  = (g - row * 6) * 4;
        int rd  = row / RH;
        int rh  = row - rd * RH;
        return min(lo_d + rd, D - 1) * HW + min(lo_h + rh, H - 1) * W
             + min(lo_w + rw, W - 4);
    };

    // async stage one channel: 6 full rounds + 102-granule ds_write tail
    auto issue_stage = [&](const float* src) {
#pragma unroll
        for (int i = 0; i < NFULL; ++i) {
            int g = tid + i * NT;                       // < 3072 < CHG
            gload_lds16(src + gsrc_off(g), &smem[g * 4]);
        }
        if (tid < TAILN) {
            int g = tid + NFULL * NT;                   // 3072..3173
            float4 v = *reinterpret_cast<const float4*>(src + gsrc_off(g));
            *reinterpret_cast<float4*>(&smem[g * 4]) = v;
        }
    };

    issue_stage(imgb);                                  // ch0 in flight
    asm volatile("" ::: "memory");

    // clamped coords, 8 voxels (24 VGPR, persisted across both passes)
    float cdk[8], chk[8], cwk[8];
    {
        const float a0[4] = {f0d.x, f0d.y, f0d.z, f0d.w};
        const float a1[4] = {f1d.x, f1d.y, f1d.z, f1d.w};
        const float b0[4] = {f0h.x, f0h.y, f0h.z, f0h.w};
        const float b1[4] = {f1h.x, f1h.y, f1h.z, f1h.w};
        const float c0[4] = {f0w.x, f0w.y, f0w.z, f0w.w};
        const float c1[4] = {f1w.x, f1w.y, f1w.z, f1w.w};
#pragma unroll
        for (int k = 0; k < 4; ++k) {
            cdk[k]     = fminf(fmaxf((float)d + a0[k], 0.0f), (float)(D - 1));
            cdk[4 + k] = fminf(fmaxf((float)d + a1[k], 0.0f), (float)(D - 1));
            chk[k]     = fminf(fmaxf((float)hh + b0[k], 0.0f), (float)(H - 1));
            chk[4 + k] = fminf(fmaxf((float)(hh + 8) + b1[k], 0.0f), (float)(H - 1));
            cwk[k]     = fminf(fmaxf((float)(w4 + k) + c0[k], 0.0f), (float)(W - 1));
            cwk[4 + k] = fminf(fmaxf((float)(w4 + k) + c1[k], 0.0f), (float)(W - 1));
        }
    }

    // one pass: branchless LDS gather of 8 voxels + rare global fixup + store
    auto do_pass = [&](const float* gimg, float* obase) {
#pragma unroll
        for (int r = 0; r < 2; ++r) {
            float acc[4];
            int fb = 0;
#pragma unroll
            for (int k = 0; k < 4; ++k) {
                int v = r * 4 + k;
                float cd = cdk[v], ch = chk[v], cw = cwk[v];
                float d0f = floorf(cd), h0f = floorf(ch), w0f = floorf(cw);
                float fd = cd - d0f, fh = ch - h0f, fw = cw - w0f;
                int d0 = (int)d0f, h0 = (int)h0f, w0 = (int)w0f;
                bool bad = (d0 < lo_d) | (d0 + 1 > hi_d)
                         | (h0 < lo_h) | (h0 + 1 > hi_h)
                         | (w0 < lo_w) | (w0 + 1 > hi_w);
                fb |= (int)bad << k;
                float gd = 1.0f - fd, gh = 1.0f - fh, gw = 1.0f - fw;
                float w00 = gh * gw, w01 = gh * fw, w10 = fh * gw, w11 = fh * fw;
                int i00 = ((d0 - lo_d) * RH + (h0 - lo_h)) * RWP + (w0 - lo_w);
                int i01 = i00 + RWP;             // h0+1
                int i10 = i00 + RH * RWP;        // d0+1
                int i11 = i10 + RWP;
                float p0 = smem[i00] * w00 + smem[i00 + 1] * w01
                         + smem[i01] * w10 + smem[i01 + 1] * w11;
                float p1 = smem[i10] * w00 + smem[i10 + 1] * w01
                         + smem[i11] * w10 + smem[i11 + 1] * w11;
                acc[k] = gd * p0 + fd * p1;      // garbage if bad (overwritten)
            }
            if (fb) {                            // rare: exact global recompute
#pragma unroll
                for (int k = 0; k < 4; ++k) {
                    if (fb & (1 << k)) {
                        int v = r * 4 + k;
                        float cd = cdk[v], ch = chk[v], cw = cwk[v];
                        float d0f = floorf(cd), h0f = floorf(ch), w0f = floorf(cw);
                        float fd = cd - d0f, fh = ch - h0f, fw = cw - w0f;
                        int d0 = (int)d0f, h0 = (int)h0f, w0 = (int)w0f;
                        int d1 = min(d0 + 1, D - 1);
                        int h1 = min(h0 + 1, H - 1);
                        int w1 = min(w0 + 1, W - 1);
                        float gd = 1.0f - fd, gh = 1.0f - fh, gw = 1.0f - fw;
                        float w00 = gh * gw, w01 = gh * fw, w10 = fh * gw, w11 = fh * fw;
                        int o00 = d0 * HW + h0 * W, o01 = d0 * HW + h1 * W;
                        int o10 = d1 * HW + h0 * W, o11 = d1 * HW + h1 * W;
                        float q0 = gimg[o00 + w0] * w00 + gimg[o00 + w1] * w01
                                 + gimg[o01 + w0] * w10 + gimg[o01 + w1] * w11;
                        float q1 = gimg[o10 + w0] * w00 + gimg[o10 + w1] * w01
                                 + gimg[o11 + w0] * w10 + gimg[o11 + w1] * w11;
                        acc[k] = gd * q0 + fd * q1;
                    }
                }
            }
            *reinterpret_cast<float4*>(obase + (r ? sidx1 : sidx0)) =
                make_float4(acc[0], acc[1], acc[2], acc[3]);
        }
    };

    // ---- pass 0 ----
    asm volatile("s_waitcnt vmcnt(0) lgkmcnt(0)" ::: "memory");
    __builtin_amdgcn_s_barrier();
    do_pass(imgb, out + ((size_t)b * C + 0) * DHW);

    __builtin_amdgcn_s_barrier();                       // ch0 reads done
    asm volatile("" ::: "memory");

    // ---- pass 1 ----
    issue_stage(imgb + DHW);
    asm volatile("s_waitcnt vmcnt(0) lgkmcnt(0)" ::: "memory");
    __builtin_amdgcn_s_barrier();
    do_pass(imgb + DHW, out + ((size_t)b * C + 1) * DHW);
}

extern "C" void kernel_launch(void* const* d_in, const int* in_sizes, int n_in,
                              void* d_out, int out_size, void* d_ws, size_t ws_size,
                              hipStream_t stream) {
    const float* image = (const float*)d_in[0];
    const float* ddf   = (const float*)d_in[1];
    float* out = (float*)d_out;

    int grid = B * 512;   // 8x8x8 tiles of 16^3 per batch
    stn_kernel<<<grid, NT, 0, stream>>>(image, ddf, out);
}